// Round 1
// baseline (152.483 us; speedup 1.0000x reference)
//
#include <hip/hip_runtime.h>
#include <stdint.h>

typedef float f32x4 __attribute__((ext_vector_type(4)));
typedef short bf16x8 __attribute__((ext_vector_type(8)));
typedef uint32_t u32;

// d_ws layout (u32 units): fragment-ordered bf16 weights
#define W1_OFF 0u       // 16 kt * 4 nt  frags, 256 u32 each
#define W2_OFF 16384u   //  2 kt * 4 nt
#define W3_OFF 18432u   //  2 kt * 32 nt
#define W4_OFF 34816u   // 16 kt * 32 nt
#define WS_BYTES (165888u * 4u)

__device__ __forceinline__ u32 f2bf(float f) {
  u32 b = __builtin_bit_cast(u32, f);
  return (b + 0x7FFFu + ((b >> 16) & 1u)) >> 16;  // RNE bf16
}
__device__ __forceinline__ u32 pack2(float lo, float hi) {
  return f2bf(lo) | (f2bf(hi) << 16);
}
__device__ __forceinline__ bf16x8 ld_frag(const u32* p) {
  union { uint4 u; bf16x8 v; } t;
  t.u = *reinterpret_cast<const uint4*>(p);
  return t.v;
}
__device__ __forceinline__ f32x4 mfma16(bf16x8 a, bf16x8 b, f32x4 c) {
  return __builtin_amdgcn_mfma_f32_16x16x32_bf16(a, b, c, 0, 0, 0);
}

// ---------------- prep: repack weights into fragment-ordered bf16 ----------------
// frag element j of lane l holds W[kt*32 + 4*(l>>4) + (j&3) + 16*(j>>2)][nt*16 + (l&15)]
__global__ void prep_kernel(const float* __restrict__ W1, const float* __restrict__ W2,
                            const float* __restrict__ W3, const float* __restrict__ W4,
                            u32* __restrict__ ws) {
  int t = blockIdx.x * 256 + threadIdx.x;
  if (t >= 648 * 64) return;
  int f = t >> 6, l = t & 63;
  const float* W; int N, NT, fi; u32 off;
  if (f < 64)       { W = W1; N = 64;  NT = 4;  fi = f;       off = W1_OFF; }
  else if (f < 72)  { W = W2; N = 64;  NT = 4;  fi = f - 64;  off = W2_OFF; }
  else if (f < 136) { W = W3; N = 512; NT = 32; fi = f - 72;  off = W3_OFF; }
  else              { W = W4; N = 512; NT = 32; fi = f - 136; off = W4_OFF; }
  int kt = fi / NT, nt = fi % NT;
  int g = l >> 4, i = l & 15;
  int n = nt * 16 + i;
  int kb = kt * 32 + 4 * g;
  u32 w0 = pack2(W[(size_t)(kb + 0) * N + n],  W[(size_t)(kb + 1) * N + n]);
  u32 w1 = pack2(W[(size_t)(kb + 2) * N + n],  W[(size_t)(kb + 3) * N + n]);
  u32 w2 = pack2(W[(size_t)(kb + 16) * N + n], W[(size_t)(kb + 17) * N + n]);
  u32 w3 = pack2(W[(size_t)(kb + 18) * N + n], W[(size_t)(kb + 19) * N + n]);
  *reinterpret_cast<uint4*>(ws + off + (u32)fi * 256u + (u32)l * 4u) = make_uint4(w0, w1, w2, w3);
}

// ---------------- fused main kernel ----------------
// 512 blocks x 256 threads; each wave owns 16 rows; wave-private 16KB LDS stripe.
__global__ __launch_bounds__(256, 2) void fused_kernel(
    const float* __restrict__ x, const float* __restrict__ noise,
    const u32* __restrict__ ws,
    const float* __restrict__ b1, const float* __restrict__ b2,
    const float* __restrict__ b3, const float* __restrict__ b4,
    const float* __restrict__ omega, const float* __restrict__ Kp,
    const float* __restrict__ alphap, float* __restrict__ out) {
  __shared__ __align__(16) char buf[65536];
  const int tid = threadIdx.x;
  const int wave = tid >> 6, l = tid & 63;
  const int g = l >> 4, i = l & 15;
  char* wbuf = buf + wave * 16384;
  const int m0 = blockIdx.x * 64 + wave * 16;  // global row base for this wave

  // ---- GEMM1: x[16x512] @ W1[512x64]
  f32x4 acc1[4] = {};
  {
    const float* xr = x + (size_t)(m0 + i) * 512 + 4 * g;
#pragma unroll
    for (int kt = 0; kt < 16; ++kt) {
      const float4 a0 = *reinterpret_cast<const float4*>(xr + kt * 32);
      const float4 a1 = *reinterpret_cast<const float4*>(xr + kt * 32 + 16);
      union { u32 u[4]; bf16x8 v; } af;
      af.u[0] = pack2(a0.x, a0.y); af.u[1] = pack2(a0.z, a0.w);
      af.u[2] = pack2(a1.x, a1.y); af.u[3] = pack2(a1.z, a1.w);
#pragma unroll
      for (int nt = 0; nt < 4; ++nt) {
        bf16x8 bf = ld_frag(ws + W1_OFF + (u32)(kt * 4 + nt) * 256u + (u32)l * 4u);
        acc1[nt] = mfma16(af.v, bf, acc1[nt]);
      }
    }
  }
  // bias + tanh -> LDS h1 [16 m][64 k] bf16, XOR-swizzled rows (stride 128B)
#pragma unroll
  for (int nt = 0; nt < 4; ++nt) {
    int k = nt * 16 + i;
    float bb = b1[k];
#pragma unroll
    for (int r = 0; r < 4; ++r) {
      int m = 4 * g + r;
      *reinterpret_cast<uint16_t*>(wbuf + m * 128 + ((2 * k) ^ ((m & 7) << 4))) =
          (uint16_t)f2bf(tanhf(acc1[nt][r] + bb));
    }
  }

  // ---- GEMM2 A-frags (row = i, k-slice per group) from LDS
  bf16x8 aph[2];
#pragma unroll
  for (int kt2 = 0; kt2 < 2; ++kt2) {
    union { uint2 u[2]; bf16x8 v; } t;
#pragma unroll
    for (int h = 0; h < 2; ++h) {
      int kb = 2 * (kt2 * 32 + 4 * g + 16 * h);
      t.u[h] = *reinterpret_cast<const uint2*>(wbuf + i * 128 + (kb ^ ((i & 7) << 4)));
    }
    aph[kt2] = t.v;
  }
  f32x4 acc2[4] = {};
#pragma unroll
  for (int kt2 = 0; kt2 < 2; ++kt2)
#pragma unroll
    for (int nt = 0; nt < 4; ++nt)
      acc2[nt] = mfma16(aph[kt2], ld_frag(ws + W2_OFF + (u32)(kt2 * 4 + nt) * 256u + (u32)l * 4u), acc2[nt]);

  // ---- Kuramoto (in-register; mean over 64 osc = 4 local regs + 16-lane butterfly)
  float ph[4][4], om[4];
  const float Kc = Kp[0];
#pragma unroll
  for (int nt = 0; nt < 4; ++nt) {
    int o = nt * 16 + i;
    float bb = b2[o];
    om[nt] = omega[o];
#pragma unroll
    for (int r = 0; r < 4; ++r) ph[nt][r] = acc2[nt][r] + bb;
  }
#pragma unroll
  for (int s = 0; s < 10; ++s) {
    float rs[4] = {0.f, 0.f, 0.f, 0.f};
    float cs[4][4];
#pragma unroll
    for (int nt = 0; nt < 4; ++nt)
#pragma unroll
      for (int r = 0; r < 4; ++r) {
        rs[r] += __sinf(ph[nt][r]);
        cs[nt][r] = __cosf(ph[nt][r]);
      }
#pragma unroll
    for (int d = 1; d < 16; d <<= 1)
#pragma unroll
      for (int r = 0; r < 4; ++r) rs[r] += __shfl_xor(rs[r], d);
#pragma unroll
    for (int nt = 0; nt < 4; ++nt)
#pragma unroll
      for (int r = 0; r < 4; ++r)
        ph[nt][r] += 0.01f * (om[nt] + Kc * (rs[r] * 0.015625f) * cs[nt][r]);
  }

  // ---- phases -> LDS (same region), reload as GEMM3 A-frags
#pragma unroll
  for (int nt = 0; nt < 4; ++nt) {
    int k = nt * 16 + i;
#pragma unroll
    for (int r = 0; r < 4; ++r) {
      int m = 4 * g + r;
      *reinterpret_cast<uint16_t*>(wbuf + m * 128 + ((2 * k) ^ ((m & 7) << 4))) =
          (uint16_t)f2bf(ph[nt][r]);
    }
  }
  bf16x8 aph2[2];
#pragma unroll
  for (int kt2 = 0; kt2 < 2; ++kt2) {
    union { uint2 u[2]; bf16x8 v; } t;
#pragma unroll
    for (int h = 0; h < 2; ++h) {
      int kb = 2 * (kt2 * 32 + 4 * g + 16 * h);
      t.u[h] = *reinterpret_cast<const uint2*>(wbuf + i * 128 + (kb ^ ((i & 7) << 4)));
    }
    aph2[kt2] = t.v;
  }

  // ---- GEMM3: phases[16x64] @ W3[64x512], relu -> fT LDS [16 m][512 k] bf16 swizzled
#pragma unroll
  for (int c = 0; c < 4; ++c) {
    f32x4 acc3[8] = {};
#pragma unroll
    for (int kt2 = 0; kt2 < 2; ++kt2)
#pragma unroll
      for (int nt = 0; nt < 8; ++nt)
        acc3[nt] = mfma16(aph2[kt2],
                          ld_frag(ws + W3_OFF + (u32)(kt2 * 32 + c * 8 + nt) * 256u + (u32)l * 4u),
                          acc3[nt]);
#pragma unroll
    for (int nt = 0; nt < 8; ++nt) {
      int col = c * 128 + nt * 16 + i;
      float bb = b3[col];
#pragma unroll
      for (int r = 0; r < 4; ++r) {
        int m = 4 * g + r;
        float v = acc3[nt][r] + bb;
        v = v > 0.f ? v : 0.f;
        *reinterpret_cast<uint16_t*>(wbuf + m * 1024 + ((2 * col) ^ ((m & 7) << 4))) =
            (uint16_t)f2bf(v);
      }
    }
  }

  // ---- GEMM4 A-frags: all 16 K-tiles resident in registers (64 VGPRs)
  bf16x8 afr[16];
#pragma unroll
  for (int kt = 0; kt < 16; ++kt) {
    union { uint2 u[2]; bf16x8 v; } t;
#pragma unroll
    for (int h = 0; h < 2; ++h) {
      int kb = 2 * (kt * 32 + 4 * g + 16 * h);
      t.u[h] = *reinterpret_cast<const uint2*>(wbuf + i * 1024 + (kb ^ ((i & 7) << 4)));
    }
    afr[kt] = t.v;
  }

  // ---- GEMM4: f[16x512] @ W4[512x512] + fused quaternion epilogue
  const float alpha = alphap[0];
#pragma unroll
  for (int c = 0; c < 4; ++c) {
    f32x4 acc[8] = {};
#pragma unroll
    for (int kt = 0; kt < 16; ++kt)
#pragma unroll
      for (int nt = 0; nt < 8; ++nt)
        acc[nt] = mfma16(afr[kt],
                         ld_frag(ws + W4_OFF + (u32)(kt * 32 + c * 8 + nt) * 256u + (u32)l * 4u),
                         acc[nt]);
#pragma unroll
    for (int nt = 0; nt < 8; ++nt) {
      int col = c * 128 + nt * 16 + i;
      float bb = b4[col];
      float fmv = __sinf(alpha * (float)col);
#pragma unroll
      for (int r = 0; r < 4; ++r) {
        int row = m0 + 4 * g + r;
        size_t idx = (size_t)row * 512 + col;
        float im = noise[idx] * fmv;
        float4 o = make_float4(acc[nt][r] + bb, im, im, im);
        *reinterpret_cast<float4*>(out + idx * 4) = o;
      }
    }
  }
}

extern "C" void kernel_launch(void* const* d_in, const int* in_sizes, int n_in,
                              void* d_out, int out_size, void* d_ws, size_t ws_size,
                              hipStream_t stream) {
  if (ws_size < WS_BYTES) return;  // need 648 KB fragment-ordered weights
  const float* x      = (const float*)d_in[0];
  const float* noise  = (const float*)d_in[1];
  const float* W1     = (const float*)d_in[2];
  const float* b1     = (const float*)d_in[3];
  const float* W2     = (const float*)d_in[4];
  const float* b2     = (const float*)d_in[5];
  const float* W3     = (const float*)d_in[6];
  const float* b3     = (const float*)d_in[7];
  const float* W4     = (const float*)d_in[8];
  const float* b4     = (const float*)d_in[9];
  const float* omega  = (const float*)d_in[10];
  const float* Kp     = (const float*)d_in[11];
  const float* alphap = (const float*)d_in[12];
  u32* ws = (u32*)d_ws;
  prep_kernel<<<162, 256, 0, stream>>>(W1, W2, W3, W4, ws);
  fused_kernel<<<512, 256, 0, stream>>>(x, noise, ws, b1, b2, b3, b4,
                                        omega, Kp, alphap, (float*)d_out);
}